// Round 2
// baseline (627.511 us; speedup 1.0000x reference)
//
#include <hip/hip_runtime.h>

// GCN 3-layer: h = relu(Ahat @ (h W) + b) x2, then Ahat @ (h W2) + b2.
// Ahat = D^-1/2 (A + I) D^-1/2, aggregation over incoming edges (dst-indexed).

static inline size_t alignup(size_t x, size_t a) { return (x + a - 1) & ~(a - 1); }

__global__ __launch_bounds__(256) void k_fill_i32(int* __restrict__ p, int v, int n) {
    int i = blockIdx.x * 256 + threadIdx.x;
    if (i < n) p[i] = v;
}

__global__ __launch_bounds__(256) void k_count_deg(const int* __restrict__ dst, int* __restrict__ deg, int E) {
    int e = blockIdx.x * 256 + threadIdx.x;
    if (e < E) atomicAdd(&deg[dst[e]], 1);
}

__global__ __launch_bounds__(256) void k_dinv(const int* __restrict__ deg, float* __restrict__ dinv, int n) {
    int i = blockIdx.x * 256 + threadIdx.x;
    if (i < n) dinv[i] = rsqrtf((float)deg[i] + 1.0f);  // +1 self-loop; always > 0
}

// ---- exclusive scan of deg -> row_start (3-kernel, 1024 elems/block) ----
__global__ __launch_bounds__(256) void k_scan1(const int* __restrict__ deg, int* __restrict__ rs,
                                               int* __restrict__ bsum, int n) {
    __shared__ int sd[256];
    int b = blockIdx.x, tid = threadIdx.x;
    int base = b * 1024 + tid * 4;
    int v[4];
#pragma unroll
    for (int j = 0; j < 4; ++j) v[j] = (base + j < n) ? deg[base + j] : 0;
    int tot = v[0] + v[1] + v[2] + v[3];
    sd[tid] = tot;
    for (int off = 1; off < 256; off <<= 1) {
        __syncthreads();
        int t = (tid >= off) ? sd[tid - off] : 0;
        __syncthreads();
        sd[tid] += t;
    }
    __syncthreads();
    int run = tid ? sd[tid - 1] : 0;  // block-local exclusive
#pragma unroll
    for (int j = 0; j < 4; ++j) {
        if (base + j < n) rs[base + j] = run;
        run += v[j];
    }
    if (tid == 255) bsum[b] = sd[255];
}

__global__ __launch_bounds__(256) void k_scan2(int* __restrict__ bsum, int nb) {
    __shared__ int sd[256];
    int tid = threadIdx.x;
    sd[tid] = (tid < nb) ? bsum[tid] : 0;
    for (int off = 1; off < 256; off <<= 1) {
        __syncthreads();
        int t = (tid >= off) ? sd[tid - off] : 0;
        __syncthreads();
        sd[tid] += t;
    }
    __syncthreads();
    if (tid < nb) bsum[tid] = tid ? sd[tid - 1] : 0;  // exclusive block offsets
}

__global__ __launch_bounds__(256) void k_scan3(int* __restrict__ rs, int* __restrict__ cursor,
                                               const int* __restrict__ bsum, int n, int E) {
    int b = blockIdx.x, tid = threadIdx.x;
    int off = bsum[b];
    int base = b * 1024 + tid * 4;
#pragma unroll
    for (int j = 0; j < 4; ++j) {
        int idx = base + j;
        if (idx < n) {
            int v = rs[idx] + off;
            rs[idx] = v;
            cursor[idx] = v;
        }
    }
    if (b == 0 && tid == 0) rs[n] = E;
}

__global__ __launch_bounds__(256) void k_fill_csr(const int* __restrict__ src, const int* __restrict__ dst,
                                                  int* __restrict__ cursor, int* __restrict__ col, int E) {
    int e = blockIdx.x * 256 + threadIdx.x;
    if (e < E) {
        int d = dst[e];
        int pos = atomicAdd(&cursor[d], 1);
        col[pos] = src[e];
    }
}

// ---- f32 GEMM: C[N][256] = A[N][256] @ B[256][256] ----
// 64x64 tile, BK=16, 256 threads, 4x4 microtile, float4 LDS reads.
#define BM 64
#define BN 64
#define BK 16

__global__ __launch_bounds__(256) void k_gemm(const float* __restrict__ A, const float* __restrict__ B,
                                              float* __restrict__ C, int N) {
    __shared__ float As[BK][BM + 4];  // +4 pad keeps float4 alignment, breaks bank stride
    __shared__ float Bs[BK][BN];
    int tid = threadIdx.x;
    int bx = blockIdx.x, by = blockIdx.y;
    int tx = tid & 15, ty = tid >> 4;
    int row0 = by * BM;
    float acc[4][4] = {};
    int ar = tid >> 2, ac = (tid & 3) << 2;   // A tile: 64 rows x 16 cols, float4/thread
    int br = tid >> 4, bc = (tid & 15) << 2;  // B tile: 16 rows x 64 cols, float4/thread

    for (int k0 = 0; k0 < 256; k0 += BK) {
        int grow = row0 + ar;
        float4 av = make_float4(0.f, 0.f, 0.f, 0.f);
        if (grow < N) av = *(const float4*)(A + (size_t)grow * 256 + k0 + ac);
        As[ac + 0][ar] = av.x;
        As[ac + 1][ar] = av.y;
        As[ac + 2][ar] = av.z;
        As[ac + 3][ar] = av.w;
        float4 bv = *(const float4*)(B + (size_t)(k0 + br) * 256 + bx * BN + bc);
        *(float4*)&Bs[br][bc] = bv;
        __syncthreads();
#pragma unroll
        for (int k = 0; k < BK; ++k) {
            float4 a4 = *(const float4*)&As[k][ty << 2];
            float4 b4 = *(const float4*)&Bs[k][tx << 2];
            float a[4] = {a4.x, a4.y, a4.z, a4.w};
            float b[4] = {b4.x, b4.y, b4.z, b4.w};
#pragma unroll
            for (int i = 0; i < 4; ++i)
#pragma unroll
                for (int j = 0; j < 4; ++j) acc[i][j] = fmaf(a[i], b[j], acc[i][j]);
        }
        __syncthreads();
    }
#pragma unroll
    for (int i = 0; i < 4; ++i) {
        int grow = row0 + (ty << 2) + i;
        if (grow < N)
            *(float4*)(C + (size_t)grow * 256 + bx * BN + (tx << 2)) =
                make_float4(acc[i][0], acc[i][1], acc[i][2], acc[i][3]);
    }
}

// ---- aggregation: h[i] = relu?(dinv_i * (sum_{src in N(i)} dinv_src * t[src] + dinv_i * t[i]) + b)
// one wave per node, float4 per lane (64*4 = 256 features)
__global__ __launch_bounds__(256) void k_agg(const float* __restrict__ t, float* __restrict__ h,
                                             const int* __restrict__ rs, const int* __restrict__ col,
                                             const float* __restrict__ dinv, const float* __restrict__ bias,
                                             int N, int do_relu) {
    int wid = (blockIdx.x * 256 + threadIdx.x) >> 6;
    int lane = threadIdx.x & 63;
    if (wid >= N) return;
    float din = dinv[wid];
    float4 tv = ((const float4*)(t + (size_t)wid * 256))[lane];
    float4 acc = make_float4(din * tv.x, din * tv.y, din * tv.z, din * tv.w);
    int e0 = rs[wid], e1 = rs[wid + 1];
    for (int e = e0; e < e1; ++e) {
        int s = col[e];
        float ds = dinv[s];
        float4 sv = ((const float4*)(t + (size_t)s * 256))[lane];
        acc.x = fmaf(ds, sv.x, acc.x);
        acc.y = fmaf(ds, sv.y, acc.y);
        acc.z = fmaf(ds, sv.z, acc.z);
        acc.w = fmaf(ds, sv.w, acc.w);
    }
    float4 bv = ((const float4*)bias)[lane];
    float4 o = make_float4(fmaf(din, acc.x, bv.x), fmaf(din, acc.y, bv.y),
                           fmaf(din, acc.z, bv.z), fmaf(din, acc.w, bv.w));
    if (do_relu) {
        o.x = fmaxf(o.x, 0.f);
        o.y = fmaxf(o.y, 0.f);
        o.z = fmaxf(o.z, 0.f);
        o.w = fmaxf(o.w, 0.f);
    }
    ((float4*)(h + (size_t)wid * 256))[lane] = o;
}

// ---- z[i] = dot(h[i,:], W2[:,0]) — one wave per node ----
__global__ __launch_bounds__(256) void k_gemv(const float* __restrict__ h, const float* __restrict__ w,
                                              float* __restrict__ z, int N) {
    int wid = (blockIdx.x * 256 + threadIdx.x) >> 6;
    int lane = threadIdx.x & 63;
    if (wid >= N) return;
    float4 hv = ((const float4*)(h + (size_t)wid * 256))[lane];
    float4 wv = ((const float4*)w)[lane];
    float s = hv.x * wv.x + hv.y * wv.y + hv.z * wv.z + hv.w * wv.w;
#pragma unroll
    for (int off = 32; off > 0; off >>= 1) s += __shfl_down(s, off, 64);
    if (lane == 0) z[wid] = s;
}

__global__ __launch_bounds__(256) void k_agg_out(const float* __restrict__ z, float* __restrict__ out,
                                                 const int* __restrict__ rs, const int* __restrict__ col,
                                                 const float* __restrict__ dinv, const float* __restrict__ b2,
                                                 int N) {
    int i = blockIdx.x * 256 + threadIdx.x;
    if (i >= N) return;
    float din = dinv[i];
    float acc = din * z[i];
    int e0 = rs[i], e1 = rs[i + 1];
    for (int e = e0; e < e1; ++e) {
        int s = col[e];
        acc = fmaf(dinv[s], z[s], acc);
    }
    out[i] = fmaf(din, acc, b2[0]);
}

extern "C" void kernel_launch(void* const* d_in, const int* in_sizes, int n_in,
                              void* d_out, int out_size, void* d_ws, size_t ws_size,
                              hipStream_t stream) {
    const float* x  = (const float*)d_in[0];
    const int*   ei = (const int*)d_in[1];
    const float* W0 = (const float*)d_in[2];
    const float* b0 = (const float*)d_in[3];
    const float* W1 = (const float*)d_in[4];
    const float* b1 = (const float*)d_in[5];
    const float* W2 = (const float*)d_in[6];
    const float* b2 = (const float*)d_in[7];
    float* out = (float*)d_out;

    int N = in_sizes[0] / 256;
    int E = in_sizes[1] / 2;
    const int* esrc = ei;
    const int* edst = ei + E;

    char* p = (char*)d_ws;
    float* t = (float*)p;      p += (size_t)N * 256 * 4;
    float* h = (float*)p;      p += (size_t)N * 256 * 4;
    float* z = (float*)p;      p += alignup((size_t)N * 4, 16);
    float* dinv = (float*)p;   p += alignup((size_t)N * 4, 16);
    int* deg = (int*)p;        p += alignup((size_t)N * 4, 16);
    int* cursor = (int*)p;     p += alignup((size_t)N * 4, 16);
    int* rs = (int*)p;         p += alignup((size_t)(N + 1) * 4, 16);
    int* col = (int*)p;        p += alignup((size_t)E * 4, 16);
    int* bsum = (int*)p;       p += 256 * 4;

    int nb = (N + 1023) / 1024;  // <= 256 required by k_scan2 (49 for N=50000)
    dim3 blk(256);

    k_fill_i32<<<(N + 255) / 256, blk, 0, stream>>>(deg, 0, N);
    k_count_deg<<<(E + 255) / 256, blk, 0, stream>>>(edst, deg, E);
    k_dinv<<<(N + 255) / 256, blk, 0, stream>>>(deg, dinv, N);
    k_scan1<<<nb, blk, 0, stream>>>(deg, rs, bsum, N);
    k_scan2<<<1, blk, 0, stream>>>(bsum, nb);
    k_scan3<<<nb, blk, 0, stream>>>(rs, cursor, bsum, N, E);
    k_fill_csr<<<(E + 255) / 256, blk, 0, stream>>>(esrc, edst, cursor, col, E);

    dim3 g0(256 / BN, (N + BM - 1) / BM);
    k_gemm<<<g0, blk, 0, stream>>>(x, W0, t, N);
    k_agg<<<(N + 3) / 4, blk, 0, stream>>>(t, h, rs, col, dinv, b0, N, 1);
    k_gemm<<<g0, blk, 0, stream>>>(h, W1, t, N);
    k_agg<<<(N + 3) / 4, blk, 0, stream>>>(t, h, rs, col, dinv, b1, N, 1);
    k_gemv<<<(N + 3) / 4, blk, 0, stream>>>(h, W2, z, N);
    k_agg_out<<<(N + 255) / 256, blk, 0, stream>>>(z, out, rs, col, dinv, b2, N);
}